// Round 3
// baseline (582.876 us; speedup 1.0000x reference)
//
#include <hip/hip_runtime.h>
#include <stdint.h>

typedef __attribute__((ext_vector_type(8))) short short8;
typedef __attribute__((ext_vector_type(4))) float floatx4;

__device__ inline unsigned short f2bf(float f) {
    union { float f; unsigned u; } v; v.f = f;
    unsigned u = v.u;
    u += 0x7fffu + ((u >> 16) & 1u);
    return (unsigned short)(u >> 16);
}
__device__ inline unsigned char f2fp8(float f) {  // OCP e4m3 via HW pack (RNE)
    int r = __builtin_amdgcn_cvt_pk_fp8_f32(f, f, 0, false);
    return (unsigned char)(r & 0xff);
}

// ---------- edge dtype detect ----------
__global__ void k_detect(const unsigned* __restrict__ w, int* __restrict__ flag, int nwords) {
    unsigned a = 0;
    for (int i = 1 + 2 * (int)threadIdx.x; i < nwords; i += 512) a |= w[i];
    if (threadIdx.x == 0) *flag = 0;
    __syncthreads();
    if (a) *flag = 1;  // benign race: all writers write 1 (int32 layout)
}

// ---------- remap + coarse bucket histogram (bucket = dst>>9) ----------
__global__ void k_remap_hist(const void* __restrict__ ei_raw, const int* __restrict__ flag,
                             int* __restrict__ src, int* __restrict__ dst,
                             int* __restrict__ bhist, int E, int n, int NB) {
    __shared__ int lh[256];
    int t = threadIdx.x;  // 1024
    if (t < 256) lh[t] = 0;
    __syncthreads();
    int base = blockIdx.x * 4096;
    bool is32 = (*flag != 0);
#pragma unroll
    for (int j = 0; j < 4; j++) {
        int e = base + j * 1024 + t;
        if (e < E) {
            int s, d;
            if (is32) { const int* p = (const int*)ei_raw; s = p[e]; d = p[E + e]; }
            else      { const long long* p = (const long long*)ei_raw; s = (int)p[e]; d = (int)p[E + e]; }
            s = s < 0 ? 0 : (s >= n ? n - 1 : s);
            d = d < 0 ? 0 : (d >= n ? n - 1 : d);
            src[e] = s; dst[e] = d;
            atomicAdd(&lh[d >> 9], 1);
        }
    }
    __syncthreads();
    if (t < NB && lh[t]) atomicAdd(&bhist[t], lh[t]);
}

// ---------- scan bucket hist -> bbase, pcur; row_ptr[N]=E ----------
__global__ void k_offsets(const int* __restrict__ bhist, int* __restrict__ bbase,
                          int* __restrict__ pcur, int* __restrict__ row_ptr,
                          int E, int n, int NB) {
    __shared__ int sc[256], orig[256];
    int t = threadIdx.x;  // 256
    int v = (t < NB) ? bhist[t] : 0;
    orig[t] = v; sc[t] = v;
    __syncthreads();
    for (int off = 1; off < 256; off <<= 1) {
        int x = (t >= off) ? sc[t - off] : 0;
        __syncthreads();
        sc[t] += x;
        __syncthreads();
    }
    if (t < NB) {
        int e = sc[t] - orig[t];
        bbase[t] = e; pcur[t] = e;
    }
    if (t == NB) bbase[t] = E;
    if (t == 0) row_ptr[n] = E;
}

// ---------- phase 1: group edges by coarse bucket (coalesced runs) ----------
__global__ void k_phase1(const int* __restrict__ src, const int* __restrict__ dst,
                         int* __restrict__ pcur, unsigned* __restrict__ pairs, int E, int NB) {
    __shared__ int lh[256];
    __shared__ int gbase[256];
    int t = threadIdx.x;  // 1024
    if (t < 256) lh[t] = 0;
    __syncthreads();
    int base = blockIdx.x * 16384;
    int rank[16], dreg[16];
#pragma unroll
    for (int j = 0; j < 16; j++) {
        int e = base + j * 1024 + t;
        dreg[j] = -1;
        if (e < E) {
            int d = dst[e];
            dreg[j] = d;
            rank[j] = atomicAdd(&lh[d >> 9], 1);
        }
    }
    __syncthreads();
    if (t < NB && lh[t]) gbase[t] = atomicAdd(&pcur[t], lh[t]);
    __syncthreads();
#pragma unroll
    for (int j = 0; j < 16; j++) {
        int e = base + j * 1024 + t;
        if (e < E) {
            int s = src[e];
            int d = dreg[j];
            pairs[gbase[d >> 9] + rank[j]] = ((unsigned)s << 9) | (unsigned)(d & 511);
        }
    }
}

// ---------- phase 2: per-bucket fine sort via LDS; row_ptr/inv_deg inline ----------
__global__ void k_phase2(const unsigned* __restrict__ pairs, const int* __restrict__ bbase,
                         int* __restrict__ row_ptr, float* __restrict__ inv_deg,
                         int* __restrict__ col, int n) {
    __shared__ int lcount[512];
    __shared__ int sc[512];
    __shared__ int lcur[512];
    int t = threadIdx.x;  // 512
    int b = blockIdx.x;
    lcount[t] = 0;
    __syncthreads();
    int e0 = bbase[b], e1 = bbase[b + 1];
    for (int i = e0 + t; i < e1; i += 512) {
        unsigned v = pairs[i];
        atomicAdd(&lcount[v & 511u], 1);
    }
    __syncthreads();
    sc[t] = lcount[t];
    __syncthreads();
    for (int off = 1; off < 512; off <<= 1) {
        int x = (t >= off) ? sc[t - off] : 0;
        __syncthreads();
        sc[t] += x;
        __syncthreads();
    }
    int excl = sc[t] - lcount[t];
    lcur[t] = excl;
    int g = b * 512 + t;
    if (g < n) {
        row_ptr[g] = e0 + excl;
        int c = lcount[t];
        inv_deg[g] = 1.0f / (float)(c > 1 ? c : 1);
    }
    __syncthreads();
    for (int i = e0 + t; i < e1; i += 512) {
        unsigned v = pairs[i];
        int f = v & 511u;
        int p = atomicAdd(&lcur[f], 1);
        col[e0 + p] = (int)(v >> 9);
    }
}

// ---------- weight fragment prep ----------
__global__ void k_w0prep(const float* __restrict__ wl, const float* __restrict__ wr,
                         const float* __restrict__ wn, unsigned short* __restrict__ W0f) {
    int tid = blockIdx.x * 256 + threadIdx.x;  // < 6144
    int lane = tid & 63; int ks = (tid >> 6) & 3; int ct = tid >> 8;
    int o = ct * 16 + (lane & 15);
    int k0 = ks * 32 + (lane >> 4) * 8;
    const float* sp = (o < 128) ? (wl + o * 128)
                    : (o < 256) ? (wr + (o - 128) * 128)
                                : (wn + (o - 256) * 128);
    union { unsigned short u[8]; short8 v; } pk;
#pragma unroll
    for (int j = 0; j < 8; j++) pk.u[j] = f2bf(sp[k0 + j]);
    ((short8*)W0f)[(ct * 4 + ks) * 64 + lane] = pk.v;
}

__global__ void k_w1prep(const float* __restrict__ wpl, const float* __restrict__ wnl,
                         const float* __restrict__ wpr, const float* __restrict__ wnr,
                         unsigned short* __restrict__ W1f) {
    int tid = blockIdx.x * 256 + threadIdx.x;  // < 8192
    int lane = tid & 63; int ks = (tid >> 6) & 7; int ct = tid >> 9;
    int o = ct * 16 + (lane & 15);
    int k0 = ks * 32 + (lane >> 4) * 8;
    union { unsigned short u[8]; short8 v; } pk;
#pragma unroll
    for (int j = 0; j < 8; j++) {
        int k = k0 + j;
        float v;
        if (o < 64)        v = (k < 128) ? wpl[o * 128 + k] : 0.0f;
        else if (o < 128)  v = (k >= 128) ? wnl[(o - 64) * 128 + (k - 128)] : 0.0f;
        else if (o < 192)  v = wpr[(o - 128) * 256 + k];
        else               v = wnr[(o - 192) * 256 + k];
        pk.u[j] = f2bf(v);
    }
    ((short8*)W1f)[(ct * 8 + ks) * 64 + lane] = pk.v;
}

// ---------- GEMM0: [P|Q|R] = x @ [w0_pos_l|w0_pos_r|w0_neg_r].T ----------
// P -> fp8 e4m3 (pre-aggregation); Q/R -> h fp32 (+biases)
// Fused: column sum/sumsq of the R half (h cols 128..255) -> colsum/colsumsq.
// v3: 6 column-tile groups of 1 (Bf live 16 VGPRs). The (256,4) bound empirically
//     caps VGPRs at 64 on this toolchain (two kernels measured at exactly 64 +
//     scratch traffic); demand must be <=64 or spills stream to HBM.
__launch_bounds__(256, 4)
__global__ void k_gemm0(const float* __restrict__ x, const unsigned short* __restrict__ W0f,
                        const float* __restrict__ b0p, const float* __restrict__ b0n,
                        unsigned char* __restrict__ P, float* __restrict__ h,
                        float* __restrict__ colsum, float* __restrict__ colsumsq, int n) {
    __shared__ unsigned short As[64 * 136];
    int t = threadIdx.x; int wave = t >> 6; int lane = t & 63;
    const short8* wf = (const short8*)W0f;
    int rowbase = blockIdx.x * 64;
    bool full = (rowbase + 64 <= n);
    if (full) {
#pragma unroll
        for (int it = 0; it < 4; it++) {
            int seg = it * 256 + t;
            int r = seg >> 4; int k0 = (seg & 15) * 8;
            const float* xp = x + (size_t)(rowbase + r) * 128 + k0;
            float4 a = *(const float4*)xp;
            float4 b = *(const float4*)(xp + 4);
            union { unsigned short u[8]; uint4 q; } pk;
            pk.u[0] = f2bf(a.x); pk.u[1] = f2bf(a.y); pk.u[2] = f2bf(a.z); pk.u[3] = f2bf(a.w);
            pk.u[4] = f2bf(b.x); pk.u[5] = f2bf(b.y); pk.u[6] = f2bf(b.z); pk.u[7] = f2bf(b.w);
            *(uint4*)(&As[r * 136 + k0]) = pk.q;
        }
    } else {
#pragma unroll
        for (int it = 0; it < 4; it++) {
            int seg = it * 256 + t;
            int r = seg >> 4; int k0 = (seg & 15) * 8;
            int row = rowbase + r;
            float4 a = {0, 0, 0, 0}, b = {0, 0, 0, 0};
            if (row < n) {
                a = *(const float4*)(x + (size_t)row * 128 + k0);
                b = *(const float4*)(x + (size_t)row * 128 + k0 + 4);
            }
            union { unsigned short u[8]; uint4 q; } pk;
            pk.u[0] = f2bf(a.x); pk.u[1] = f2bf(a.y); pk.u[2] = f2bf(a.z); pk.u[3] = f2bf(a.w);
            pk.u[4] = f2bf(b.x); pk.u[5] = f2bf(b.y); pk.u[6] = f2bf(b.z); pk.u[7] = f2bf(b.w);
            *(uint4*)(&As[r * 136 + k0]) = pk.q;
        }
    }
    __syncthreads();
    int m = lane & 15; int quad = lane >> 4;
    float cs[6], cq[6];
#pragma unroll
    for (int i = 0; i < 6; i++) { cs[i] = 0.f; cq[i] = 0.f; }
#pragma unroll
    for (int g = 0; g < 6; g++) {
        short8 Bf[4];
        int ct = wave * 6 + g;
#pragma unroll
        for (int ks = 0; ks < 4; ks++) Bf[ks] = wf[(ct * 4 + ks) * 64 + lane];
        int colg = wave * 96 + g * 16 + m;
#pragma unroll
        for (int rt = 0; rt < 4; rt++) {
            floatx4 acc = (floatx4){0.f, 0.f, 0.f, 0.f};
#pragma unroll
            for (int ks = 0; ks < 4; ks++) {
                short8 a = *(const short8*)(&As[(rt * 16 + m) * 136 + ks * 32 + quad * 8]);
                acc = __builtin_amdgcn_mfma_f32_16x16x32_bf16(a, Bf[ks], acc, 0, 0, 0);
            }
            int r0 = rowbase + rt * 16 + quad * 4;
            if (full) {
                if (colg < 128) {
                    unsigned char* pp = P + (size_t)r0 * 128 + colg;
                    pp[0]   = f2fp8(acc[0]);
                    pp[128] = f2fp8(acc[1]);
                    pp[256] = f2fp8(acc[2]);
                    pp[384] = f2fp8(acc[3]);
                } else {
                    float bias = (colg < 256) ? b0p[colg - 128] : b0n[colg - 256];
                    float v0 = acc[0] + bias, v1 = acc[1] + bias;
                    float v2 = acc[2] + bias, v3 = acc[3] + bias;
                    float* hp = h + (size_t)r0 * 256 + (colg - 128);
                    hp[0] = v0; hp[256] = v1; hp[512] = v2; hp[768] = v3;
                    if (colg >= 256) {
                        cs[g] += v0 + v1 + v2 + v3;
                        cq[g] += v0 * v0 + v1 * v1 + v2 * v2 + v3 * v3;
                    }
                }
            } else {
                float bias = 0.f;
                if (colg >= 128 && colg < 256) bias = b0p[colg - 128];
                else if (colg >= 256)          bias = b0n[colg - 256];
#pragma unroll
                for (int rr = 0; rr < 4; rr++) {
                    int row = r0 + rr;
                    if (row < n) {
                        float v = acc[rr] + bias;
                        if (colg < 128) {
                            P[(size_t)row * 128 + colg] = f2fp8(v);
                        } else {
                            h[(size_t)row * 256 + (colg - 128)] = v;
                            if (colg >= 256) { cs[g] += v; cq[g] += v * v; }
                        }
                    }
                }
            }
        }
    }
#pragma unroll
    for (int i = 0; i < 6; i++) {
        int colg = wave * 96 + i * 16 + m;
        if (colg >= 256) {
            float s = cs[i];
            s += __shfl_xor(s, 16); s += __shfl_xor(s, 32);
            float q = cq[i];
            q += __shfl_xor(q, 16); q += __shfl_xor(q, 32);
            if (quad == 0) {
                atomicAdd(&colsum[colg - 128], s);
                atomicAdd(&colsumsq[colg - 128], q);
            }
        }
    }
}

// ---------- aggregation: grid-strided waves over dst nodes; split-wave fp8 gather ----------
// If STATS: accumulate column sum/sumsq of the FINAL written values (h cols 0..127).
template<int OSTRIDE, bool STATS>
__global__ __launch_bounds__(256) void k_agg(const int* __restrict__ row_ptr,
                                             const int* __restrict__ col,
                                             const float* __restrict__ inv_deg,
                                             const unsigned* __restrict__ Prow,
                                             float* __restrict__ out,
                                             float* __restrict__ colsum,
                                             float* __restrict__ colsumsq, int n) {
    int wid = threadIdx.x >> 6, lane = threadIdx.x & 63;
    int half = lane >> 5, li = lane & 31;
    float sx = 0.f, sy = 0.f, qx = 0.f, qy = 0.f;
    for (int node = blockIdx.x * 4 + wid; node < n; node += gridDim.x * 4) {
        int e0 = row_ptr[node], e1 = row_ptr[node + 1];
        float a0 = 0.f, a1 = 0.f, a2 = 0.f, a3 = 0.f;
        for (int j = e0; j < e1; j += 64) {
            int cnt = e1 - j; if (cnt > 64) cnt = 64;
            int idx = j + lane;
            int myc = col[idx < e1 ? idx : e1 - 1];
            int i = 0;
            for (; i + 8 <= cnt; i += 8) {
                int sA = __shfl(myc, i + half);
                int sB = __shfl(myc, i + 2 + half);
                int sC = __shfl(myc, i + 4 + half);
                int sD = __shfl(myc, i + 6 + half);
                unsigned vA = Prow[(size_t)sA * 32 + li];
                unsigned vB = Prow[(size_t)sB * 32 + li];
                unsigned vC = Prow[(size_t)sC * 32 + li];
                unsigned vD = Prow[(size_t)sD * 32 + li];
                a0 += __builtin_amdgcn_cvt_f32_fp8(vA, 0); a1 += __builtin_amdgcn_cvt_f32_fp8(vA, 1);
                a2 += __builtin_amdgcn_cvt_f32_fp8(vA, 2); a3 += __builtin_amdgcn_cvt_f32_fp8(vA, 3);
                a0 += __builtin_amdgcn_cvt_f32_fp8(vB, 0); a1 += __builtin_amdgcn_cvt_f32_fp8(vB, 1);
                a2 += __builtin_amdgcn_cvt_f32_fp8(vB, 2); a3 += __builtin_amdgcn_cvt_f32_fp8(vB, 3);
                a0 += __builtin_amdgcn_cvt_f32_fp8(vC, 0); a1 += __builtin_amdgcn_cvt_f32_fp8(vC, 1);
                a2 += __builtin_amdgcn_cvt_f32_fp8(vC, 2); a3 += __builtin_amdgcn_cvt_f32_fp8(vC, 3);
                a0 += __builtin_amdgcn_cvt_f32_fp8(vD, 0); a1 += __builtin_amdgcn_cvt_f32_fp8(vD, 1);
                a2 += __builtin_amdgcn_cvt_f32_fp8(vD, 2); a3 += __builtin_amdgcn_cvt_f32_fp8(vD, 3);
            }
            for (; i + 2 <= cnt; i += 2) {
                int s = __shfl(myc, i + half);
                unsigned v = Prow[(size_t)s * 32 + li];
                a0 += __builtin_amdgcn_cvt_f32_fp8(v, 0); a1 += __builtin_amdgcn_cvt_f32_fp8(v, 1);
                a2 += __builtin_amdgcn_cvt_f32_fp8(v, 2); a3 += __builtin_amdgcn_cvt_f32_fp8(v, 3);
            }
            if (i < cnt) {
                int s = __shfl(myc, i);  // all lanes participate in the shuffle
                if (half == 0) {
                    unsigned v = Prow[(size_t)s * 32 + li];
                    a0 += __builtin_amdgcn_cvt_f32_fp8(v, 0); a1 += __builtin_amdgcn_cvt_f32_fp8(v, 1);
                    a2 += __builtin_amdgcn_cvt_f32_fp8(v, 2); a3 += __builtin_amdgcn_cvt_f32_fp8(v, 3);
                }
            }
        }
        a0 += __shfl_xor(a0, 32);
        a1 += __shfl_xor(a1, 32);
        a2 += __shfl_xor(a2, 32);
        a3 += __shfl_xor(a3, 32);
        float idg = inv_deg[node];
        float rx = half ? a2 : a0;
        float ry = half ? a3 : a1;
        float* o = out + (size_t)node * OSTRIDE + 4 * li + 2 * half;
        float2 q = *(const float2*)o;
        float2 r;
        r.x = rx * idg + q.x;
        r.y = ry * idg + q.y;
        *(float2*)o = r;
        if (STATS) { sx += r.x; sy += r.y; qx += r.x * r.x; qy += r.y * r.y; }
    }
    if (STATS) {
        __shared__ float S[4][128], Q[4][128];
        int c0 = 4 * li + 2 * half;
        S[wid][c0] = sx; S[wid][c0 + 1] = sy;
        Q[wid][c0] = qx; Q[wid][c0 + 1] = qy;
        __syncthreads();
        int t = threadIdx.x;
        if (t < 128) {
            atomicAdd(&colsum[t], S[0][t] + S[1][t] + S[2][t] + S[3][t]);
            atomicAdd(&colsumsq[t], Q[0][t] + Q[1][t] + Q[2][t] + Q[3][t]);
        }
    }
}

__global__ void k_bnfin(const float* __restrict__ colsum, const float* __restrict__ colsumsq,
                        const float* __restrict__ gamma, const float* __restrict__ beta,
                        float* __restrict__ scale, float* __restrict__ shift, int n) {
    int t = threadIdx.x;
    float inv_n = 1.0f / (float)n;
    float mu = colsum[t] * inv_n;
    float var = colsumsq[t] * inv_n - mu * mu;
    float sc = gamma[t] * rsqrtf(var + 1e-5f);
    scale[t] = sc;
    shift[t] = beta[t] - mu * sc;
}

// ---------- GEMM1: fused BN-affine + ReLU + [Y|Z] ----------
// v3: 4 column-tile groups of 1 (Bf live set 32 VGPRs; fits the empirical 64-VGPR
//     cap of (256,4)). Uniform full-block fast path, base-pointer epilogue stores.
__launch_bounds__(256, 4)
__global__ void k_gemm1(const float* __restrict__ h, const unsigned short* __restrict__ W1f,
                        const float* __restrict__ bnscale, const float* __restrict__ bnshift,
                        const float* __restrict__ b1p, const float* __restrict__ b1n,
                        unsigned char* __restrict__ Y, float* __restrict__ out, int n) {
    __shared__ unsigned short As[64 * 264];
    __shared__ float sc[256], sh[256];
    int t = threadIdx.x; int wave = t >> 6; int lane = t & 63;
    sc[t] = bnscale[t]; sh[t] = bnshift[t];
    const short8* wf = (const short8*)W1f;
    int rowbase = blockIdx.x * 64;
    bool full = (rowbase + 64 <= n);
    __syncthreads();
    if (full) {
#pragma unroll
        for (int it = 0; it < 8; it++) {
            int seg = it * 256 + t;
            int r = seg >> 5; int k0 = (seg & 31) * 8;
            const float* hp = h + (size_t)(rowbase + r) * 256 + k0;
            float4 a = *(const float4*)hp;
            float4 b = *(const float4*)(hp + 4);
            float vv[8] = {a.x, a.y, a.z, a.w, b.x, b.y, b.z, b.w};
            union { unsigned short u[8]; uint4 q; } pk;
#pragma unroll
            for (int q2 = 0; q2 < 8; q2++) {
                float v = vv[q2] * sc[k0 + q2] + sh[k0 + q2];
                v = v > 0.f ? v : 0.f;
                pk.u[q2] = f2bf(v);
            }
            *(uint4*)(&As[r * 264 + k0]) = pk.q;
        }
    } else {
#pragma unroll
        for (int it = 0; it < 8; it++) {
            int seg = it * 256 + t;
            int r = seg >> 5; int k0 = (seg & 31) * 8;
            int row = rowbase + r;
            union { unsigned short u[8]; uint4 q; } pk;
            if (row < n) {
                float4 a = *(const float4*)(h + (size_t)row * 256 + k0);
                float4 b = *(const float4*)(h + (size_t)row * 256 + k0 + 4);
                float vv[8] = {a.x, a.y, a.z, a.w, b.x, b.y, b.z, b.w};
#pragma unroll
                for (int q2 = 0; q2 < 8; q2++) {
                    float v = vv[q2] * sc[k0 + q2] + sh[k0 + q2];
                    v = v > 0.f ? v : 0.f;
                    pk.u[q2] = f2bf(v);
                }
            } else {
#pragma unroll
                for (int q2 = 0; q2 < 8; q2++) pk.u[q2] = 0;
            }
            *(uint4*)(&As[r * 264 + k0]) = pk.q;
        }
    }
    __syncthreads();
    int m = lane & 15; int quad = lane >> 4;
#pragma unroll
    for (int g = 0; g < 4; g++) {
        short8 Bf[8];
        int ct = wave * 4 + g;
#pragma unroll
        for (int ks = 0; ks < 8; ks++) Bf[ks] = wf[(ct * 8 + ks) * 64 + lane];
        int colg = wave * 64 + g * 16 + m;
#pragma unroll
        for (int rt = 0; rt < 4; rt++) {
            floatx4 acc = (floatx4){0.f, 0.f, 0.f, 0.f};
#pragma unroll
            for (int ks = 0; ks < 8; ks++) {
                short8 a = *(const short8*)(&As[(rt * 16 + m) * 264 + ks * 32 + quad * 8]);
                acc = __builtin_amdgcn_mfma_f32_16x16x32_bf16(a, Bf[ks], acc, 0, 0, 0);
            }
            int r0 = rowbase + rt * 16 + quad * 4;
            if (full) {
                if (colg < 128) {
                    unsigned char* yp = Y + (size_t)r0 * 128 + colg;
                    yp[0]   = f2fp8(acc[0]);
                    yp[128] = f2fp8(acc[1]);
                    yp[256] = f2fp8(acc[2]);
                    yp[384] = f2fp8(acc[3]);
                } else {
                    float bias = (colg < 192) ? b1p[colg - 128] : b1n[colg - 192];
                    float* op = out + (size_t)r0 * 128 + (colg - 128);
                    op[0]   = acc[0] + bias;
                    op[128] = acc[1] + bias;
                    op[256] = acc[2] + bias;
                    op[384] = acc[3] + bias;
                }
            } else {
#pragma unroll
                for (int rr = 0; rr < 4; rr++) {
                    int row = r0 + rr;
                    if (row < n) {
                        float v = acc[rr];
                        if (colg < 128) {
                            Y[(size_t)row * 128 + colg] = f2fp8(v);
                        } else {
                            float bias = (colg < 192) ? b1p[colg - 128] : b1n[colg - 192];
                            out[(size_t)row * 128 + (colg - 128)] = v + bias;
                        }
                    }
                }
            }
        }
    }
}

extern "C" void kernel_launch(void* const* d_in, const int* in_sizes, int n_in,
                              void* d_out, int out_size, void* d_ws, size_t ws_size,
                              hipStream_t stream) {
    const float* x        = (const float*)d_in[0];
    const void*  ei_raw   = d_in[1];
    const float* w0_pos_l = (const float*)d_in[2];
    const float* w0_pos_r = (const float*)d_in[3];
    const float* b0_pos_r = (const float*)d_in[4];
    const float* w0_neg_r = (const float*)d_in[5];
    const float* b0_neg_r = (const float*)d_in[6];
    const float* bn_gamma = (const float*)d_in[7];
    const float* bn_beta  = (const float*)d_in[8];
    const float* w1_pos_l = (const float*)d_in[9];
    const float* w1_pos_r = (const float*)d_in[10];
    const float* b1_pos_r = (const float*)d_in[11];
    const float* w1_neg_l = (const float*)d_in[12];
    const float* w1_neg_r = (const float*)d_in[13];
    const float* b1_neg_r = (const float*)d_in[14];
    float* out = (float*)d_out;
    int N = in_sizes[0] / 128;
    int E = in_sizes[1] / 2;
    int NB = (N + 511) >> 9;  // coarse buckets of 512 dst nodes

    char* ws = (char*)d_ws;
    size_t off = 0;
    auto carve = [&](size_t bytes) -> char* {
        char* p = ws + off;
        off += (bytes + 255) & ~(size_t)255;
        return p;
    };
    int*      eflag   = (int*)carve(256);
    int*      src     = (int*)carve((size_t)E * 4);
    int*      dst     = (int*)carve((size_t)E * 4);
    int*      bhist   = (int*)carve((size_t)NB * 4);
    int*      bbase   = (int*)carve((size_t)(NB + 1) * 4);
    int*      pcur    = (int*)carve((size_t)NB * 4);
    int*      row_ptr = (int*)carve((size_t)(N + 1) * 4);
    float*    inv_deg = (float*)carve((size_t)N * 4);
    unsigned* pairs   = (unsigned*)carve((size_t)E * 4);
    int*      ecol    = (int*)carve((size_t)E * 4);
    unsigned char* P  = (unsigned char*)carve((size_t)N * 128);
    float* h          = (float*)carve((size_t)N * 256 * 4);
    unsigned char* Yb = (unsigned char*)carve((size_t)N * 128);
    unsigned short* W0f = (unsigned short*)carve(24 * 4 * 64 * 8 * 2);
    unsigned short* W1f = (unsigned short*)carve(16 * 8 * 64 * 8 * 2);
    float* colsum   = (float*)carve(2 * 256 * 4);
    float* colsumsq = colsum + 256;
    float* bnscale  = (float*)carve(256 * 4);
    float* bnshift  = (float*)carve(256 * 4);

    hipMemsetAsync(bhist, 0, (size_t)NB * 4, stream);
    hipMemsetAsync(colsum, 0, 2 * 256 * 4, stream);

    int nwords = 2 * E < 32768 ? 2 * E : 32768;
    k_detect<<<1, 256, 0, stream>>>((const unsigned*)ei_raw, eflag, nwords);
    k_remap_hist<<<(E + 4095) / 4096, 1024, 0, stream>>>(ei_raw, eflag, src, dst, bhist, E, N, NB);
    k_offsets<<<1, 256, 0, stream>>>(bhist, bbase, pcur, row_ptr, E, N, NB);
    k_phase1<<<(E + 16383) / 16384, 1024, 0, stream>>>(src, dst, pcur, pairs, E, NB);
    k_phase2<<<NB, 512, 0, stream>>>(pairs, bbase, row_ptr, inv_deg, ecol, N);

    k_w0prep<<<24, 256, 0, stream>>>(w0_pos_l, w0_pos_r, w0_neg_r, W0f);
    k_w1prep<<<32, 256, 0, stream>>>(w1_pos_l, w1_neg_l, w1_pos_r, w1_neg_r, W1f);

    int gb = (N + 63) / 64;
    k_gemm0<<<gb, 256, 0, stream>>>(x, W0f, b0_pos_r, b0_neg_r, P, h, colsum, colsumsq, N);
    k_agg<256, true><<<2048, 256, 0, stream>>>(row_ptr, ecol, inv_deg, (const unsigned*)P, h,
                                               colsum, colsumsq, N);
    k_bnfin<<<1, 256, 0, stream>>>(colsum, colsumsq, bn_gamma, bn_beta, bnscale, bnshift, N);
    k_gemm1<<<gb, 256, 0, stream>>>(h, W1f, bnscale, bnshift, b1_pos_r, b1_neg_r, Yb, out, N);
    k_agg<128, false><<<2048, 256, 0, stream>>>(row_ptr, ecol, inv_deg, (const unsigned*)Yb, out,
                                                nullptr, nullptr, N);
}

// Round 4
// 493.477 us; speedup vs baseline: 1.1812x; 1.1812x over previous
//
#include <hip/hip_runtime.h>
#include <stdint.h>

typedef __attribute__((ext_vector_type(8))) short short8;
typedef __attribute__((ext_vector_type(4))) float floatx4;

__device__ inline unsigned short f2bf(float f) {
    union { float f; unsigned u; } v; v.f = f;
    unsigned u = v.u;
    u += 0x7fffu + ((u >> 16) & 1u);
    return (unsigned short)(u >> 16);
}
__device__ inline unsigned char f2fp8(float f) {  // OCP e4m3 via HW pack (RNE)
    int r = __builtin_amdgcn_cvt_pk_fp8_f32(f, f, 0, false);
    return (unsigned char)(r & 0xff);
}

// ---------- edge dtype detect ----------
__global__ void k_detect(const unsigned* __restrict__ w, int* __restrict__ flag, int nwords) {
    unsigned a = 0;
    for (int i = 1 + 2 * (int)threadIdx.x; i < nwords; i += 512) a |= w[i];
    if (threadIdx.x == 0) *flag = 0;
    __syncthreads();
    if (a) *flag = 1;  // benign race: all writers write 1 (int32 layout)
}

// ---------- remap + coarse bucket histogram (bucket = dst>>9) ----------
__global__ void k_remap_hist(const void* __restrict__ ei_raw, const int* __restrict__ flag,
                             int* __restrict__ src, int* __restrict__ dst,
                             int* __restrict__ bhist, int E, int n, int NB) {
    __shared__ int lh[256];
    int t = threadIdx.x;  // 1024
    if (t < 256) lh[t] = 0;
    __syncthreads();
    int base = blockIdx.x * 4096;
    bool is32 = (*flag != 0);
#pragma unroll
    for (int j = 0; j < 4; j++) {
        int e = base + j * 1024 + t;
        if (e < E) {
            int s, d;
            if (is32) { const int* p = (const int*)ei_raw; s = p[e]; d = p[E + e]; }
            else      { const long long* p = (const long long*)ei_raw; s = (int)p[e]; d = (int)p[E + e]; }
            s = s < 0 ? 0 : (s >= n ? n - 1 : s);
            d = d < 0 ? 0 : (d >= n ? n - 1 : d);
            src[e] = s; dst[e] = d;
            atomicAdd(&lh[d >> 9], 1);
        }
    }
    __syncthreads();
    if (t < NB && lh[t]) atomicAdd(&bhist[t], lh[t]);
}

// ---------- scan bucket hist -> bbase, pcur; row_ptr[N]=E ----------
__global__ void k_offsets(const int* __restrict__ bhist, int* __restrict__ bbase,
                          int* __restrict__ pcur, int* __restrict__ row_ptr,
                          int E, int n, int NB) {
    __shared__ int sc[256], orig[256];
    int t = threadIdx.x;  // 256
    int v = (t < NB) ? bhist[t] : 0;
    orig[t] = v; sc[t] = v;
    __syncthreads();
    for (int off = 1; off < 256; off <<= 1) {
        int x = (t >= off) ? sc[t - off] : 0;
        __syncthreads();
        sc[t] += x;
        __syncthreads();
    }
    if (t < NB) {
        int e = sc[t] - orig[t];
        bbase[t] = e; pcur[t] = e;
    }
    if (t == NB) bbase[t] = E;
    if (t == 0) row_ptr[n] = E;
}

// ---------- phase 1: group edges by coarse bucket (coalesced runs) ----------
__global__ void k_phase1(const int* __restrict__ src, const int* __restrict__ dst,
                         int* __restrict__ pcur, unsigned* __restrict__ pairs, int E, int NB) {
    __shared__ int lh[256];
    __shared__ int gbase[256];
    int t = threadIdx.x;  // 1024
    if (t < 256) lh[t] = 0;
    __syncthreads();
    int base = blockIdx.x * 16384;
    int rank[16], dreg[16];
#pragma unroll
    for (int j = 0; j < 16; j++) {
        int e = base + j * 1024 + t;
        dreg[j] = -1;
        if (e < E) {
            int d = dst[e];
            dreg[j] = d;
            rank[j] = atomicAdd(&lh[d >> 9], 1);
        }
    }
    __syncthreads();
    if (t < NB && lh[t]) gbase[t] = atomicAdd(&pcur[t], lh[t]);
    __syncthreads();
#pragma unroll
    for (int j = 0; j < 16; j++) {
        int e = base + j * 1024 + t;
        if (e < E) {
            int s = src[e];
            int d = dreg[j];
            pairs[gbase[d >> 9] + rank[j]] = ((unsigned)s << 9) | (unsigned)(d & 511);
        }
    }
}

// ---------- phase 2: per-bucket fine sort via LDS; row_ptr/inv_deg inline ----------
__global__ void k_phase2(const unsigned* __restrict__ pairs, const int* __restrict__ bbase,
                         int* __restrict__ row_ptr, float* __restrict__ inv_deg,
                         int* __restrict__ col, int n) {
    __shared__ int lcount[512];
    __shared__ int sc[512];
    __shared__ int lcur[512];
    int t = threadIdx.x;  // 512
    int b = blockIdx.x;
    lcount[t] = 0;
    __syncthreads();
    int e0 = bbase[b], e1 = bbase[b + 1];
    for (int i = e0 + t; i < e1; i += 512) {
        unsigned v = pairs[i];
        atomicAdd(&lcount[v & 511u], 1);
    }
    __syncthreads();
    sc[t] = lcount[t];
    __syncthreads();
    for (int off = 1; off < 512; off <<= 1) {
        int x = (t >= off) ? sc[t - off] : 0;
        __syncthreads();
        sc[t] += x;
        __syncthreads();
    }
    int excl = sc[t] - lcount[t];
    lcur[t] = excl;
    int g = b * 512 + t;
    if (g < n) {
        row_ptr[g] = e0 + excl;
        int c = lcount[t];
        inv_deg[g] = 1.0f / (float)(c > 1 ? c : 1);
    }
    __syncthreads();
    for (int i = e0 + t; i < e1; i += 512) {
        unsigned v = pairs[i];
        int f = v & 511u;
        int p = atomicAdd(&lcur[f], 1);
        col[e0 + p] = (int)(v >> 9);
    }
}

// ---------- weight fragment prep ----------
__global__ void k_w0prep(const float* __restrict__ wl, const float* __restrict__ wr,
                         const float* __restrict__ wn, unsigned short* __restrict__ W0f) {
    int tid = blockIdx.x * 256 + threadIdx.x;  // < 6144
    int lane = tid & 63; int ks = (tid >> 6) & 3; int ct = tid >> 8;
    int o = ct * 16 + (lane & 15);
    int k0 = ks * 32 + (lane >> 4) * 8;
    const float* sp = (o < 128) ? (wl + o * 128)
                    : (o < 256) ? (wr + (o - 128) * 128)
                                : (wn + (o - 256) * 128);
    union { unsigned short u[8]; short8 v; } pk;
#pragma unroll
    for (int j = 0; j < 8; j++) pk.u[j] = f2bf(sp[k0 + j]);
    ((short8*)W0f)[(ct * 4 + ks) * 64 + lane] = pk.v;
}

__global__ void k_w1prep(const float* __restrict__ wpl, const float* __restrict__ wnl,
                         const float* __restrict__ wpr, const float* __restrict__ wnr,
                         unsigned short* __restrict__ W1f) {
    int tid = blockIdx.x * 256 + threadIdx.x;  // < 8192
    int lane = tid & 63; int ks = (tid >> 6) & 7; int ct = tid >> 9;
    int o = ct * 16 + (lane & 15);
    int k0 = ks * 32 + (lane >> 4) * 8;
    union { unsigned short u[8]; short8 v; } pk;
#pragma unroll
    for (int j = 0; j < 8; j++) {
        int k = k0 + j;
        float v;
        if (o < 64)        v = (k < 128) ? wpl[o * 128 + k] : 0.0f;
        else if (o < 128)  v = (k >= 128) ? wnl[(o - 64) * 128 + (k - 128)] : 0.0f;
        else if (o < 192)  v = wpr[(o - 128) * 256 + k];
        else               v = wnr[(o - 192) * 256 + k];
        pk.u[j] = f2bf(v);
    }
    ((short8*)W1f)[(ct * 8 + ks) * 64 + lane] = pk.v;
}

// ---------- GEMM0: [P|Q|R] = x @ [w0_pos_l|w0_pos_r|w0_neg_r].T ----------
// P -> fp8 e4m3 (pre-aggregation); Q/R -> h fp32 (+biases)
// Fused: column sum/sumsq of the R half (h cols 128..255) -> colsum/colsumsq.
// v4: __launch_bounds__(256,2) (the only measured spill-free config; (256,4)
//     caps arch-VGPRs at 64 and streams ~30-60MB of scratch). Column-split
//     grid x2: each block does 192 of 384 cols -> Bf[3][4]=48 regs live,
//     demand ~90 VGPR -> ~5 waves/SIMD for latency hiding. x re-read is
//     L3-absorbed (FETCH was 27MB at round 0). Uniform full-tile fast path +
//     base-pointer immediate-offset epilogue stores.
__launch_bounds__(256, 2)
__global__ void k_gemm0(const float* __restrict__ x, const unsigned short* __restrict__ W0f,
                        const float* __restrict__ b0p, const float* __restrict__ b0n,
                        unsigned char* __restrict__ P, float* __restrict__ h,
                        float* __restrict__ colsum, float* __restrict__ colsumsq, int n) {
    __shared__ unsigned short As[64 * 136];
    int t = threadIdx.x; int wave = t >> 6; int lane = t & 63;
    const short8* wf = (const short8*)W0f;
    int bx = blockIdx.x;
    int rowbase = (bx >> 1) * 64;
    int ch = bx & 1;  // column half: 0 -> cols 0..191, 1 -> cols 192..383
    bool full = (rowbase + 64 <= n);
    if (full) {
#pragma unroll
        for (int it = 0; it < 4; it++) {
            int seg = it * 256 + t;
            int r = seg >> 4; int k0 = (seg & 15) * 8;
            const float* xp = x + (size_t)(rowbase + r) * 128 + k0;
            float4 a = *(const float4*)xp;
            float4 b = *(const float4*)(xp + 4);
            union { unsigned short u[8]; uint4 q; } pk;
            pk.u[0] = f2bf(a.x); pk.u[1] = f2bf(a.y); pk.u[2] = f2bf(a.z); pk.u[3] = f2bf(a.w);
            pk.u[4] = f2bf(b.x); pk.u[5] = f2bf(b.y); pk.u[6] = f2bf(b.z); pk.u[7] = f2bf(b.w);
            *(uint4*)(&As[r * 136 + k0]) = pk.q;
        }
    } else {
#pragma unroll
        for (int it = 0; it < 4; it++) {
            int seg = it * 256 + t;
            int r = seg >> 4; int k0 = (seg & 15) * 8;
            int row = rowbase + r;
            float4 a = {0, 0, 0, 0}, b = {0, 0, 0, 0};
            if (row < n) {
                a = *(const float4*)(x + (size_t)row * 128 + k0);
                b = *(const float4*)(x + (size_t)row * 128 + k0 + 4);
            }
            union { unsigned short u[8]; uint4 q; } pk;
            pk.u[0] = f2bf(a.x); pk.u[1] = f2bf(a.y); pk.u[2] = f2bf(a.z); pk.u[3] = f2bf(a.w);
            pk.u[4] = f2bf(b.x); pk.u[5] = f2bf(b.y); pk.u[6] = f2bf(b.z); pk.u[7] = f2bf(b.w);
            *(uint4*)(&As[r * 136 + k0]) = pk.q;
        }
    }
    __syncthreads();
    int m = lane & 15; int quad = lane >> 4;
    float cs[3], cq[3];
#pragma unroll
    for (int i = 0; i < 3; i++) { cs[i] = 0.f; cq[i] = 0.f; }
    short8 Bf[3][4];
    int ctbase = ch * 12 + wave * 3;
#pragma unroll
    for (int i = 0; i < 3; i++) {
#pragma unroll
        for (int ks = 0; ks < 4; ks++) Bf[i][ks] = wf[((ctbase + i) * 4 + ks) * 64 + lane];
    }
#pragma unroll
    for (int rt = 0; rt < 4; rt++) {
        floatx4 acc[3];
#pragma unroll
        for (int i = 0; i < 3; i++) acc[i] = (floatx4){0.f, 0.f, 0.f, 0.f};
#pragma unroll
        for (int ks = 0; ks < 4; ks++) {
            short8 a = *(const short8*)(&As[(rt * 16 + m) * 136 + ks * 32 + quad * 8]);
#pragma unroll
            for (int i = 0; i < 3; i++)
                acc[i] = __builtin_amdgcn_mfma_f32_16x16x32_bf16(a, Bf[i][ks], acc[i], 0, 0, 0);
        }
        int r0 = rowbase + rt * 16 + quad * 4;
#pragma unroll
        for (int i = 0; i < 3; i++) {
            int colg = ch * 192 + wave * 48 + i * 16 + m;
            if (full) {
                if (colg < 128) {
                    unsigned char* pp = P + (size_t)r0 * 128 + colg;
                    pp[0]   = f2fp8(acc[i][0]);
                    pp[128] = f2fp8(acc[i][1]);
                    pp[256] = f2fp8(acc[i][2]);
                    pp[384] = f2fp8(acc[i][3]);
                } else {
                    float bias = (colg < 256) ? b0p[colg - 128] : b0n[colg - 256];
                    float v0 = acc[i][0] + bias, v1 = acc[i][1] + bias;
                    float v2 = acc[i][2] + bias, v3 = acc[i][3] + bias;
                    float* hp = h + (size_t)r0 * 256 + (colg - 128);
                    hp[0] = v0; hp[256] = v1; hp[512] = v2; hp[768] = v3;
                    if (colg >= 256) {
                        cs[i] += v0 + v1 + v2 + v3;
                        cq[i] += v0 * v0 + v1 * v1 + v2 * v2 + v3 * v3;
                    }
                }
            } else {
                float bias = 0.f;
                if (colg >= 128 && colg < 256) bias = b0p[colg - 128];
                else if (colg >= 256)          bias = b0n[colg - 256];
#pragma unroll
                for (int rr = 0; rr < 4; rr++) {
                    int row = r0 + rr;
                    if (row < n) {
                        float v = acc[i][rr] + bias;
                        if (colg < 128) {
                            P[(size_t)row * 128 + colg] = f2fp8(v);
                        } else {
                            h[(size_t)row * 256 + (colg - 128)] = v;
                            if (colg >= 256) { cs[i] += v; cq[i] += v * v; }
                        }
                    }
                }
            }
        }
    }
#pragma unroll
    for (int i = 0; i < 3; i++) {
        int colg = ch * 192 + wave * 48 + i * 16 + m;
        if (colg >= 256) {
            float s = cs[i];
            s += __shfl_xor(s, 16); s += __shfl_xor(s, 32);
            float q = cq[i];
            q += __shfl_xor(q, 16); q += __shfl_xor(q, 32);
            if (quad == 0) {
                atomicAdd(&colsum[colg - 128], s);
                atomicAdd(&colsumsq[colg - 128], q);
            }
        }
    }
}

// ---------- aggregation: grid-strided waves over dst nodes; split-wave fp8 gather ----------
// If STATS: accumulate column sum/sumsq of the FINAL written values (h cols 0..127).
template<int OSTRIDE, bool STATS>
__global__ __launch_bounds__(256) void k_agg(const int* __restrict__ row_ptr,
                                             const int* __restrict__ col,
                                             const float* __restrict__ inv_deg,
                                             const unsigned* __restrict__ Prow,
                                             float* __restrict__ out,
                                             float* __restrict__ colsum,
                                             float* __restrict__ colsumsq, int n) {
    int wid = threadIdx.x >> 6, lane = threadIdx.x & 63;
    int half = lane >> 5, li = lane & 31;
    float sx = 0.f, sy = 0.f, qx = 0.f, qy = 0.f;
    for (int node = blockIdx.x * 4 + wid; node < n; node += gridDim.x * 4) {
        int e0 = row_ptr[node], e1 = row_ptr[node + 1];
        float a0 = 0.f, a1 = 0.f, a2 = 0.f, a3 = 0.f;
        for (int j = e0; j < e1; j += 64) {
            int cnt = e1 - j; if (cnt > 64) cnt = 64;
            int idx = j + lane;
            int myc = col[idx < e1 ? idx : e1 - 1];
            int i = 0;
            for (; i + 8 <= cnt; i += 8) {
                int sA = __shfl(myc, i + half);
                int sB = __shfl(myc, i + 2 + half);
                int sC = __shfl(myc, i + 4 + half);
                int sD = __shfl(myc, i + 6 + half);
                unsigned vA = Prow[(size_t)sA * 32 + li];
                unsigned vB = Prow[(size_t)sB * 32 + li];
                unsigned vC = Prow[(size_t)sC * 32 + li];
                unsigned vD = Prow[(size_t)sD * 32 + li];
                a0 += __builtin_amdgcn_cvt_f32_fp8(vA, 0); a1 += __builtin_amdgcn_cvt_f32_fp8(vA, 1);
                a2 += __builtin_amdgcn_cvt_f32_fp8(vA, 2); a3 += __builtin_amdgcn_cvt_f32_fp8(vA, 3);
                a0 += __builtin_amdgcn_cvt_f32_fp8(vB, 0); a1 += __builtin_amdgcn_cvt_f32_fp8(vB, 1);
                a2 += __builtin_amdgcn_cvt_f32_fp8(vB, 2); a3 += __builtin_amdgcn_cvt_f32_fp8(vB, 3);
                a0 += __builtin_amdgcn_cvt_f32_fp8(vC, 0); a1 += __builtin_amdgcn_cvt_f32_fp8(vC, 1);
                a2 += __builtin_amdgcn_cvt_f32_fp8(vC, 2); a3 += __builtin_amdgcn_cvt_f32_fp8(vC, 3);
                a0 += __builtin_amdgcn_cvt_f32_fp8(vD, 0); a1 += __builtin_amdgcn_cvt_f32_fp8(vD, 1);
                a2 += __builtin_amdgcn_cvt_f32_fp8(vD, 2); a3 += __builtin_amdgcn_cvt_f32_fp8(vD, 3);
            }
            for (; i + 2 <= cnt; i += 2) {
                int s = __shfl(myc, i + half);
                unsigned v = Prow[(size_t)s * 32 + li];
                a0 += __builtin_amdgcn_cvt_f32_fp8(v, 0); a1 += __builtin_amdgcn_cvt_f32_fp8(v, 1);
                a2 += __builtin_amdgcn_cvt_f32_fp8(v, 2); a3 += __builtin_amdgcn_cvt_f32_fp8(v, 3);
            }
            if (i < cnt) {
                int s = __shfl(myc, i);  // all lanes participate in the shuffle
                if (half == 0) {
                    unsigned v = Prow[(size_t)s * 32 + li];
                    a0 += __builtin_amdgcn_cvt_f32_fp8(v, 0); a1 += __builtin_amdgcn_cvt_f32_fp8(v, 1);
                    a2 += __builtin_amdgcn_cvt_f32_fp8(v, 2); a3 += __builtin_amdgcn_cvt_f32_fp8(v, 3);
                }
            }
        }
        a0 += __shfl_xor(a0, 32);
        a1 += __shfl_xor(a1, 32);
        a2 += __shfl_xor(a2, 32);
        a3 += __shfl_xor(a3, 32);
        float idg = inv_deg[node];
        float rx = half ? a2 : a0;
        float ry = half ? a3 : a1;
        float* o = out + (size_t)node * OSTRIDE + 4 * li + 2 * half;
        float2 q = *(const float2*)o;
        float2 r;
        r.x = rx * idg + q.x;
        r.y = ry * idg + q.y;
        *(float2*)o = r;
        if (STATS) { sx += r.x; sy += r.y; qx += r.x * r.x; qy += r.y * r.y; }
    }
    if (STATS) {
        __shared__ float S[4][128], Q[4][128];
        int c0 = 4 * li + 2 * half;
        S[wid][c0] = sx; S[wid][c0 + 1] = sy;
        Q[wid][c0] = qx; Q[wid][c0 + 1] = qy;
        __syncthreads();
        int t = threadIdx.x;
        if (t < 128) {
            atomicAdd(&colsum[t], S[0][t] + S[1][t] + S[2][t] + S[3][t]);
            atomicAdd(&colsumsq[t], Q[0][t] + Q[1][t] + Q[2][t] + Q[3][t]);
        }
    }
}

__global__ void k_bnfin(const float* __restrict__ colsum, const float* __restrict__ colsumsq,
                        const float* __restrict__ gamma, const float* __restrict__ beta,
                        float* __restrict__ scale, float* __restrict__ shift, int n) {
    int t = threadIdx.x;
    float inv_n = 1.0f / (float)n;
    float mu = colsum[t] * inv_n;
    float var = colsumsq[t] * inv_n - mu * mu;
    float sc = gamma[t] * rsqrtf(var + 1e-5f);
    scale[t] = sc;
    shift[t] = beta[t] - mu * sc;
}

// ---------- GEMM1: fused BN-affine + ReLU + [Y|Z] ----------
// v4: __launch_bounds__(256,2) (spill-free config). Column-split grid x2:
//     each block does 128 of 256 cols -> Bf[2][8]=64 regs live, demand ~100
//     VGPR -> ~5 waves/SIMD. h re-read is L3-served. Uniform full-tile fast
//     path + base-pointer immediate-offset epilogue stores.
__launch_bounds__(256, 2)
__global__ void k_gemm1(const float* __restrict__ h, const unsigned short* __restrict__ W1f,
                        const float* __restrict__ bnscale, const float* __restrict__ bnshift,
                        const float* __restrict__ b1p, const float* __restrict__ b1n,
                        unsigned char* __restrict__ Y, float* __restrict__ out, int n) {
    __shared__ unsigned short As[64 * 264];
    __shared__ float sc[256], sh[256];
    int t = threadIdx.x; int wave = t >> 6; int lane = t & 63;
    sc[t] = bnscale[t]; sh[t] = bnshift[t];
    const short8* wf = (const short8*)W1f;
    int bx = blockIdx.x;
    int rowbase = (bx >> 1) * 64;
    int ch = bx & 1;  // column half: 0 -> cols 0..127, 1 -> cols 128..255
    bool full = (rowbase + 64 <= n);
    __syncthreads();
    if (full) {
#pragma unroll
        for (int it = 0; it < 8; it++) {
            int seg = it * 256 + t;
            int r = seg >> 5; int k0 = (seg & 31) * 8;
            const float* hp = h + (size_t)(rowbase + r) * 256 + k0;
            float4 a = *(const float4*)hp;
            float4 b = *(const float4*)(hp + 4);
            float vv[8] = {a.x, a.y, a.z, a.w, b.x, b.y, b.z, b.w};
            union { unsigned short u[8]; uint4 q; } pk;
#pragma unroll
            for (int q2 = 0; q2 < 8; q2++) {
                float v = vv[q2] * sc[k0 + q2] + sh[k0 + q2];
                v = v > 0.f ? v : 0.f;
                pk.u[q2] = f2bf(v);
            }
            *(uint4*)(&As[r * 264 + k0]) = pk.q;
        }
    } else {
#pragma unroll
        for (int it = 0; it < 8; it++) {
            int seg = it * 256 + t;
            int r = seg >> 5; int k0 = (seg & 31) * 8;
            int row = rowbase + r;
            union { unsigned short u[8]; uint4 q; } pk;
            if (row < n) {
                float4 a = *(const float4*)(h + (size_t)row * 256 + k0);
                float4 b = *(const float4*)(h + (size_t)row * 256 + k0 + 4);
                float vv[8] = {a.x, a.y, a.z, a.w, b.x, b.y, b.z, b.w};
#pragma unroll
                for (int q2 = 0; q2 < 8; q2++) {
                    float v = vv[q2] * sc[k0 + q2] + sh[k0 + q2];
                    v = v > 0.f ? v : 0.f;
                    pk.u[q2] = f2bf(v);
                }
            } else {
#pragma unroll
                for (int q2 = 0; q2 < 8; q2++) pk.u[q2] = 0;
            }
            *(uint4*)(&As[r * 264 + k0]) = pk.q;
        }
    }
    __syncthreads();
    int m = lane & 15; int quad = lane >> 4;
    short8 Bf[2][8];
    int ctbase = ch * 8 + wave * 2;
#pragma unroll
    for (int i = 0; i < 2; i++) {
#pragma unroll
        for (int ks = 0; ks < 8; ks++) Bf[i][ks] = wf[((ctbase + i) * 8 + ks) * 64 + lane];
    }
#pragma unroll
    for (int rt = 0; rt < 4; rt++) {
        floatx4 acc[2];
        acc[0] = (floatx4){0.f, 0.f, 0.f, 0.f};
        acc[1] = (floatx4){0.f, 0.f, 0.f, 0.f};
#pragma unroll
        for (int ks = 0; ks < 8; ks++) {
            short8 a = *(const short8*)(&As[(rt * 16 + m) * 264 + ks * 32 + quad * 8]);
            acc[0] = __builtin_amdgcn_mfma_f32_16x16x32_bf16(a, Bf[0][ks], acc[0], 0, 0, 0);
            acc[1] = __builtin_amdgcn_mfma_f32_16x16x32_bf16(a, Bf[1][ks], acc[1], 0, 0, 0);
        }
        int r0 = rowbase + rt * 16 + quad * 4;
#pragma unroll
        for (int i = 0; i < 2; i++) {
            int colg = ch * 128 + wave * 32 + i * 16 + m;
            if (full) {
                if (colg < 128) {
                    unsigned char* yp = Y + (size_t)r0 * 128 + colg;
                    yp[0]   = f2fp8(acc[i][0]);
                    yp[128] = f2fp8(acc[i][1]);
                    yp[256] = f2fp8(acc[i][2]);
                    yp[384] = f2fp8(acc[i][3]);
                } else {
                    float bias = (colg < 192) ? b1p[colg - 128] : b1n[colg - 192];
                    float* op = out + (size_t)r0 * 128 + (colg - 128);
                    op[0]   = acc[i][0] + bias;
                    op[128] = acc[i][1] + bias;
                    op[256] = acc[i][2] + bias;
                    op[384] = acc[i][3] + bias;
                }
            } else {
#pragma unroll
                for (int rr = 0; rr < 4; rr++) {
                    int row = r0 + rr;
                    if (row < n) {
                        float v = acc[i][rr];
                        if (colg < 128) {
                            Y[(size_t)row * 128 + colg] = f2fp8(v);
                        } else {
                            float bias = (colg < 192) ? b1p[colg - 128] : b1n[colg - 192];
                            out[(size_t)row * 128 + (colg - 128)] = v + bias;
                        }
                    }
                }
            }
        }
    }
}

extern "C" void kernel_launch(void* const* d_in, const int* in_sizes, int n_in,
                              void* d_out, int out_size, void* d_ws, size_t ws_size,
                              hipStream_t stream) {
    const float* x        = (const float*)d_in[0];
    const void*  ei_raw   = d_in[1];
    const float* w0_pos_l = (const float*)d_in[2];
    const float* w0_pos_r = (const float*)d_in[3];
    const float* b0_pos_r = (const float*)d_in[4];
    const float* w0_neg_r = (const float*)d_in[5];
    const float* b0_neg_r = (const float*)d_in[6];
    const float* bn_gamma = (const float*)d_in[7];
    const float* bn_beta  = (const float*)d_in[8];
    const float* w1_pos_l = (const float*)d_in[9];
    const float* w1_pos_r = (const float*)d_in[10];
    const float* b1_pos_r = (const float*)d_in[11];
    const float* w1_neg_l = (const float*)d_in[12];
    const float* w1_neg_r = (const float*)d_in[13];
    const float* b1_neg_r = (const float*)d_in[14];
    float* out = (float*)d_out;
    int N = in_sizes[0] / 128;
    int E = in_sizes[1] / 2;
    int NB = (N + 511) >> 9;  // coarse buckets of 512 dst nodes

    char* ws = (char*)d_ws;
    size_t off = 0;
    auto carve = [&](size_t bytes) -> char* {
        char* p = ws + off;
        off += (bytes + 255) & ~(size_t)255;
        return p;
    };
    int*      eflag   = (int*)carve(256);
    int*      src     = (int*)carve((size_t)E * 4);
    int*      dst     = (int*)carve((size_t)E * 4);
    int*      bhist   = (int*)carve((size_t)NB * 4);
    int*      bbase   = (int*)carve((size_t)(NB + 1) * 4);
    int*      pcur    = (int*)carve((size_t)NB * 4);
    int*      row_ptr = (int*)carve((size_t)(N + 1) * 4);
    float*    inv_deg = (float*)carve((size_t)N * 4);
    unsigned* pairs   = (unsigned*)carve((size_t)E * 4);
    int*      ecol    = (int*)carve((size_t)E * 4);
    unsigned char* P  = (unsigned char*)carve((size_t)N * 128);
    float* h          = (float*)carve((size_t)N * 256 * 4);
    unsigned char* Yb = (unsigned char*)carve((size_t)N * 128);
    unsigned short* W0f = (unsigned short*)carve(24 * 4 * 64 * 8 * 2);
    unsigned short* W1f = (unsigned short*)carve(16 * 8 * 64 * 8 * 2);
    float* colsum   = (float*)carve(2 * 256 * 4);
    float* colsumsq = colsum + 256;
    float* bnscale  = (float*)carve(256 * 4);
    float* bnshift  = (float*)carve(256 * 4);

    hipMemsetAsync(bhist, 0, (size_t)NB * 4, stream);
    hipMemsetAsync(colsum, 0, 2 * 256 * 4, stream);

    int nwords = 2 * E < 32768 ? 2 * E : 32768;
    k_detect<<<1, 256, 0, stream>>>((const unsigned*)ei_raw, eflag, nwords);
    k_remap_hist<<<(E + 4095) / 4096, 1024, 0, stream>>>(ei_raw, eflag, src, dst, bhist, E, N, NB);
    k_offsets<<<1, 256, 0, stream>>>(bhist, bbase, pcur, row_ptr, E, N, NB);
    k_phase1<<<(E + 16383) / 16384, 1024, 0, stream>>>(src, dst, pcur, pairs, E, NB);
    k_phase2<<<NB, 512, 0, stream>>>(pairs, bbase, row_ptr, inv_deg, ecol, N);

    k_w0prep<<<24, 256, 0, stream>>>(w0_pos_l, w0_pos_r, w0_neg_r, W0f);
    k_w1prep<<<32, 256, 0, stream>>>(w1_pos_l, w1_neg_l, w1_pos_r, w1_neg_r, W1f);

    int gb = (N + 63) / 64;
    k_gemm0<<<gb * 2, 256, 0, stream>>>(x, W0f, b0_pos_r, b0_neg_r, P, h, colsum, colsumsq, N);
    k_agg<256, true><<<2048, 256, 0, stream>>>(row_ptr, ecol, inv_deg, (const unsigned*)P, h,
                                               colsum, colsumsq, N);
    k_bnfin<<<1, 256, 0, stream>>>(colsum, colsumsq, bn_gamma, bn_beta, bnscale, bnshift, N);
    k_gemm1<<<gb * 2, 256, 0, stream>>>(h, W1f, bnscale, bnshift, b1_pos_r, b1_neg_r, Yb, out, N);
    k_agg<128, false><<<2048, 256, 0, stream>>>(row_ptr, ecol, inv_deg, (const unsigned*)Yb, out,
                                                nullptr, nullptr, N);
}

// Round 5
// 492.093 us; speedup vs baseline: 1.1845x; 1.0028x over previous
//
#include <hip/hip_runtime.h>
#include <stdint.h>

typedef __attribute__((ext_vector_type(8))) short short8;
typedef __attribute__((ext_vector_type(4))) float floatx4;
typedef __attribute__((ext_vector_type(2))) float floatx2;

__device__ inline unsigned short f2bf(float f) {
    union { float f; unsigned u; } v; v.f = f;
    unsigned u = v.u;
    u += 0x7fffu + ((u >> 16) & 1u);
    return (unsigned short)(u >> 16);
}
__device__ inline unsigned char f2fp8(float f) {  // OCP e4m3 via HW pack (RNE)
    int r = __builtin_amdgcn_cvt_pk_fp8_f32(f, f, 0, false);
    return (unsigned char)(r & 0xff);
}

// ---------- edge dtype detect ----------
__global__ void k_detect(const unsigned* __restrict__ w, int* __restrict__ flag, int nwords) {
    unsigned a = 0;
    for (int i = 1 + 2 * (int)threadIdx.x; i < nwords; i += 512) a |= w[i];
    if (threadIdx.x == 0) *flag = 0;
    __syncthreads();
    if (a) *flag = 1;  // benign race: all writers write 1 (int32 layout)
}

// ---------- remap + coarse bucket histogram (bucket = dst>>9) ----------
__global__ void k_remap_hist(const void* __restrict__ ei_raw, const int* __restrict__ flag,
                             int* __restrict__ src, int* __restrict__ dst,
                             int* __restrict__ bhist, int E, int n, int NB) {
    __shared__ int lh[256];
    int t = threadIdx.x;  // 1024
    if (t < 256) lh[t] = 0;
    __syncthreads();
    int base = blockIdx.x * 4096;
    bool is32 = (*flag != 0);
#pragma unroll
    for (int j = 0; j < 4; j++) {
        int e = base + j * 1024 + t;
        if (e < E) {
            int s, d;
            if (is32) { const int* p = (const int*)ei_raw; s = p[e]; d = p[E + e]; }
            else      { const long long* p = (const long long*)ei_raw; s = (int)p[e]; d = (int)p[E + e]; }
            s = s < 0 ? 0 : (s >= n ? n - 1 : s);
            d = d < 0 ? 0 : (d >= n ? n - 1 : d);
            src[e] = s; dst[e] = d;
            atomicAdd(&lh[d >> 9], 1);
        }
    }
    __syncthreads();
    if (t < NB && lh[t]) atomicAdd(&bhist[t], lh[t]);
}

// ---------- scan bucket hist -> bbase, pcur; row_ptr[N]=E ----------
__global__ void k_offsets(const int* __restrict__ bhist, int* __restrict__ bbase,
                          int* __restrict__ pcur, int* __restrict__ row_ptr,
                          int E, int n, int NB) {
    __shared__ int sc[256], orig[256];
    int t = threadIdx.x;  // 256
    int v = (t < NB) ? bhist[t] : 0;
    orig[t] = v; sc[t] = v;
    __syncthreads();
    for (int off = 1; off < 256; off <<= 1) {
        int x = (t >= off) ? sc[t - off] : 0;
        __syncthreads();
        sc[t] += x;
        __syncthreads();
    }
    if (t < NB) {
        int e = sc[t] - orig[t];
        bbase[t] = e; pcur[t] = e;
    }
    if (t == NB) bbase[t] = E;
    if (t == 0) row_ptr[n] = E;
}

// ---------- phase 1: group edges by coarse bucket (coalesced runs) ----------
__global__ void k_phase1(const int* __restrict__ src, const int* __restrict__ dst,
                         int* __restrict__ pcur, unsigned* __restrict__ pairs, int E, int NB) {
    __shared__ int lh[256];
    __shared__ int gbase[256];
    int t = threadIdx.x;  // 1024
    if (t < 256) lh[t] = 0;
    __syncthreads();
    int base = blockIdx.x * 16384;
    int rank[16], dreg[16];
#pragma unroll
    for (int j = 0; j < 16; j++) {
        int e = base + j * 1024 + t;
        dreg[j] = -1;
        if (e < E) {
            int d = dst[e];
            dreg[j] = d;
            rank[j] = atomicAdd(&lh[d >> 9], 1);
        }
    }
    __syncthreads();
    if (t < NB && lh[t]) gbase[t] = atomicAdd(&pcur[t], lh[t]);
    __syncthreads();
#pragma unroll
    for (int j = 0; j < 16; j++) {
        int e = base + j * 1024 + t;
        if (e < E) {
            int s = src[e];
            int d = dreg[j];
            pairs[gbase[d >> 9] + rank[j]] = ((unsigned)s << 9) | (unsigned)(d & 511);
        }
    }
}

// ---------- phase 2: per-bucket fine sort via LDS; row_ptr/inv_deg inline ----------
__global__ void k_phase2(const unsigned* __restrict__ pairs, const int* __restrict__ bbase,
                         int* __restrict__ row_ptr, float* __restrict__ inv_deg,
                         int* __restrict__ col, int n) {
    __shared__ int lcount[512];
    __shared__ int sc[512];
    __shared__ int lcur[512];
    int t = threadIdx.x;  // 512
    int b = blockIdx.x;
    lcount[t] = 0;
    __syncthreads();
    int e0 = bbase[b], e1 = bbase[b + 1];
    for (int i = e0 + t; i < e1; i += 512) {
        unsigned v = pairs[i];
        atomicAdd(&lcount[v & 511u], 1);
    }
    __syncthreads();
    sc[t] = lcount[t];
    __syncthreads();
    for (int off = 1; off < 512; off <<= 1) {
        int x = (t >= off) ? sc[t - off] : 0;
        __syncthreads();
        sc[t] += x;
        __syncthreads();
    }
    int excl = sc[t] - lcount[t];
    lcur[t] = excl;
    int g = b * 512 + t;
    if (g < n) {
        row_ptr[g] = e0 + excl;
        int c = lcount[t];
        inv_deg[g] = 1.0f / (float)(c > 1 ? c : 1);
    }
    __syncthreads();
    for (int i = e0 + t; i < e1; i += 512) {
        unsigned v = pairs[i];
        int f = v & 511u;
        int p = atomicAdd(&lcur[f], 1);
        col[e0 + p] = (int)(v >> 9);
    }
}

// ---------- weight fragment prep ----------
__global__ void k_w0prep(const float* __restrict__ wl, const float* __restrict__ wr,
                         const float* __restrict__ wn, unsigned short* __restrict__ W0f) {
    int tid = blockIdx.x * 256 + threadIdx.x;  // < 6144
    int lane = tid & 63; int ks = (tid >> 6) & 3; int ct = tid >> 8;
    int o = ct * 16 + (lane & 15);
    int k0 = ks * 32 + (lane >> 4) * 8;
    const float* sp = (o < 128) ? (wl + o * 128)
                    : (o < 256) ? (wr + (o - 128) * 128)
                                : (wn + (o - 256) * 128);
    union { unsigned short u[8]; short8 v; } pk;
#pragma unroll
    for (int j = 0; j < 8; j++) pk.u[j] = f2bf(sp[k0 + j]);
    ((short8*)W0f)[(ct * 4 + ks) * 64 + lane] = pk.v;
}

__global__ void k_w1prep(const float* __restrict__ wpl, const float* __restrict__ wnl,
                         const float* __restrict__ wpr, const float* __restrict__ wnr,
                         unsigned short* __restrict__ W1f) {
    int tid = blockIdx.x * 256 + threadIdx.x;  // < 8192
    int lane = tid & 63; int ks = (tid >> 6) & 7; int ct = tid >> 9;
    int o = ct * 16 + (lane & 15);
    int k0 = ks * 32 + (lane >> 4) * 8;
    union { unsigned short u[8]; short8 v; } pk;
#pragma unroll
    for (int j = 0; j < 8; j++) {
        int k = k0 + j;
        float v;
        if (o < 64)        v = (k < 128) ? wpl[o * 128 + k] : 0.0f;
        else if (o < 128)  v = (k >= 128) ? wnl[(o - 64) * 128 + (k - 128)] : 0.0f;
        else if (o < 192)  v = wpr[(o - 128) * 256 + k];
        else               v = wnr[(o - 192) * 256 + k];
        pk.u[j] = f2bf(v);
    }
    ((short8*)W1f)[(ct * 8 + ks) * 64 + lane] = pk.v;
}

// ---------- GEMM0: [P|Q|R] = x @ [w0_pos_l|w0_pos_r|w0_neg_r].T ----------
__launch_bounds__(256, 2)
__global__ void k_gemm0(const float* __restrict__ x, const unsigned short* __restrict__ W0f,
                        const float* __restrict__ b0p, const float* __restrict__ b0n,
                        unsigned char* __restrict__ P, float* __restrict__ h,
                        float* __restrict__ colsum, float* __restrict__ colsumsq, int n) {
    __shared__ unsigned short As[64 * 136];
    int t = threadIdx.x; int wave = t >> 6; int lane = t & 63;
    const short8* wf = (const short8*)W0f;
    int bx = blockIdx.x;
    int rowbase = (bx >> 1) * 64;
    int ch = bx & 1;  // column half: 0 -> cols 0..191, 1 -> cols 192..383
    bool full = (rowbase + 64 <= n);
    if (full) {
#pragma unroll
        for (int it = 0; it < 4; it++) {
            int seg = it * 256 + t;
            int r = seg >> 4; int k0 = (seg & 15) * 8;
            const float* xp = x + (size_t)(rowbase + r) * 128 + k0;
            float4 a = *(const float4*)xp;
            float4 b = *(const float4*)(xp + 4);
            union { unsigned short u[8]; uint4 q; } pk;
            pk.u[0] = f2bf(a.x); pk.u[1] = f2bf(a.y); pk.u[2] = f2bf(a.z); pk.u[3] = f2bf(a.w);
            pk.u[4] = f2bf(b.x); pk.u[5] = f2bf(b.y); pk.u[6] = f2bf(b.z); pk.u[7] = f2bf(b.w);
            *(uint4*)(&As[r * 136 + k0]) = pk.q;
        }
    } else {
#pragma unroll
        for (int it = 0; it < 4; it++) {
            int seg = it * 256 + t;
            int r = seg >> 4; int k0 = (seg & 15) * 8;
            int row = rowbase + r;
            float4 a = {0, 0, 0, 0}, b = {0, 0, 0, 0};
            if (row < n) {
                a = *(const float4*)(x + (size_t)row * 128 + k0);
                b = *(const float4*)(x + (size_t)row * 128 + k0 + 4);
            }
            union { unsigned short u[8]; uint4 q; } pk;
            pk.u[0] = f2bf(a.x); pk.u[1] = f2bf(a.y); pk.u[2] = f2bf(a.z); pk.u[3] = f2bf(a.w);
            pk.u[4] = f2bf(b.x); pk.u[5] = f2bf(b.y); pk.u[6] = f2bf(b.z); pk.u[7] = f2bf(b.w);
            *(uint4*)(&As[r * 136 + k0]) = pk.q;
        }
    }
    __syncthreads();
    int m = lane & 15; int quad = lane >> 4;
    float cs[3], cq[3];
#pragma unroll
    for (int i = 0; i < 3; i++) { cs[i] = 0.f; cq[i] = 0.f; }
    short8 Bf[3][4];
    int ctbase = ch * 12 + wave * 3;
#pragma unroll
    for (int i = 0; i < 3; i++) {
#pragma unroll
        for (int ks = 0; ks < 4; ks++) Bf[i][ks] = wf[((ctbase + i) * 4 + ks) * 64 + lane];
    }
#pragma unroll
    for (int rt = 0; rt < 4; rt++) {
        floatx4 acc[3];
#pragma unroll
        for (int i = 0; i < 3; i++) acc[i] = (floatx4){0.f, 0.f, 0.f, 0.f};
#pragma unroll
        for (int ks = 0; ks < 4; ks++) {
            short8 a = *(const short8*)(&As[(rt * 16 + m) * 136 + ks * 32 + quad * 8]);
#pragma unroll
            for (int i = 0; i < 3; i++)
                acc[i] = __builtin_amdgcn_mfma_f32_16x16x32_bf16(a, Bf[i][ks], acc[i], 0, 0, 0);
        }
        int r0 = rowbase + rt * 16 + quad * 4;
#pragma unroll
        for (int i = 0; i < 3; i++) {
            int colg = ch * 192 + wave * 48 + i * 16 + m;
            if (full) {
                if (colg < 128) {
                    unsigned char* pp = P + (size_t)r0 * 128 + colg;
                    pp[0]   = f2fp8(acc[i][0]);
                    pp[128] = f2fp8(acc[i][1]);
                    pp[256] = f2fp8(acc[i][2]);
                    pp[384] = f2fp8(acc[i][3]);
                } else {
                    float bias = (colg < 256) ? b0p[colg - 128] : b0n[colg - 256];
                    float v0 = acc[i][0] + bias, v1 = acc[i][1] + bias;
                    float v2 = acc[i][2] + bias, v3 = acc[i][3] + bias;
                    float* hp = h + (size_t)r0 * 256 + (colg - 128);
                    hp[0] = v0; hp[256] = v1; hp[512] = v2; hp[768] = v3;
                    if (colg >= 256) {
                        cs[i] += v0 + v1 + v2 + v3;
                        cq[i] += v0 * v0 + v1 * v1 + v2 * v2 + v3 * v3;
                    }
                }
            } else {
                float bias = 0.f;
                if (colg >= 128 && colg < 256) bias = b0p[colg - 128];
                else if (colg >= 256)          bias = b0n[colg - 256];
#pragma unroll
                for (int rr = 0; rr < 4; rr++) {
                    int row = r0 + rr;
                    if (row < n) {
                        float v = acc[i][rr] + bias;
                        if (colg < 128) {
                            P[(size_t)row * 128 + colg] = f2fp8(v);
                        } else {
                            h[(size_t)row * 256 + (colg - 128)] = v;
                            if (colg >= 256) { cs[i] += v; cq[i] += v * v; }
                        }
                    }
                }
            }
        }
    }
#pragma unroll
    for (int i = 0; i < 3; i++) {
        int colg = ch * 192 + wave * 48 + i * 16 + m;
        if (colg >= 256) {
            float s = cs[i];
            s += __shfl_xor(s, 16); s += __shfl_xor(s, 32);
            float q = cq[i];
            q += __shfl_xor(q, 16); q += __shfl_xor(q, 32);
            if (quad == 0) {
                atomicAdd(&colsum[colg - 128], s);
                atomicAdd(&colsumsq[colg - 128], q);
            }
        }
    }
}

// ---------- aggregation v2: 16-lane-group gather, dwordx2/lane, packed fp8 cvt ----------
// 4 edges per load instruction (vs 2), half the shuffles, cvt_pk+pk_add halve
// the per-edge VALU. Cross-group butterfly (xor 16/32) replaces the half-reduce.
// If STATS: accumulate column sum/sumsq of the FINAL written values (h cols 0..127).
template<int OSTRIDE, bool STATS>
__global__ __launch_bounds__(256) void k_agg(const int* __restrict__ row_ptr,
                                             const int* __restrict__ col,
                                             const float* __restrict__ inv_deg,
                                             const uint2* __restrict__ P2,
                                             float* __restrict__ out,
                                             float* __restrict__ colsum,
                                             float* __restrict__ colsumsq, int n) {
    int wid = threadIdx.x >> 6, lane = threadIdx.x & 63;
    int g = lane >> 4, li = lane & 15;
    float sx = 0.f, sy = 0.f, qx = 0.f, qy = 0.f;
    for (int node = blockIdx.x * 4 + wid; node < n; node += gridDim.x * 4) {
        int e0 = row_ptr[node], e1 = row_ptr[node + 1];
        floatx2 a01 = {0.f, 0.f}, a23 = {0.f, 0.f}, a45 = {0.f, 0.f}, a67 = {0.f, 0.f};
        for (int j = e0; j < e1; j += 64) {
            int cnt = e1 - j; if (cnt > 64) cnt = 64;
            int idx = j + lane;
            int myc = col[idx < e1 ? idx : e1 - 1];
            int i = 0;
            for (; i + 16 <= cnt; i += 16) {
                int s0 = __shfl(myc, i + g);
                int s1 = __shfl(myc, i + 4 + g);
                int s2 = __shfl(myc, i + 8 + g);
                int s3 = __shfl(myc, i + 12 + g);
                uint2 v0 = P2[(size_t)s0 * 16 + li];
                uint2 v1 = P2[(size_t)s1 * 16 + li];
                uint2 v2 = P2[(size_t)s2 * 16 + li];
                uint2 v3 = P2[(size_t)s3 * 16 + li];
                a01 += __builtin_amdgcn_cvt_pk_f32_fp8(v0.x, false);
                a23 += __builtin_amdgcn_cvt_pk_f32_fp8(v0.x, true);
                a45 += __builtin_amdgcn_cvt_pk_f32_fp8(v0.y, false);
                a67 += __builtin_amdgcn_cvt_pk_f32_fp8(v0.y, true);
                a01 += __builtin_amdgcn_cvt_pk_f32_fp8(v1.x, false);
                a23 += __builtin_amdgcn_cvt_pk_f32_fp8(v1.x, true);
                a45 += __builtin_amdgcn_cvt_pk_f32_fp8(v1.y, false);
                a67 += __builtin_amdgcn_cvt_pk_f32_fp8(v1.y, true);
                a01 += __builtin_amdgcn_cvt_pk_f32_fp8(v2.x, false);
                a23 += __builtin_amdgcn_cvt_pk_f32_fp8(v2.x, true);
                a45 += __builtin_amdgcn_cvt_pk_f32_fp8(v2.y, false);
                a67 += __builtin_amdgcn_cvt_pk_f32_fp8(v2.y, true);
                a01 += __builtin_amdgcn_cvt_pk_f32_fp8(v3.x, false);
                a23 += __builtin_amdgcn_cvt_pk_f32_fp8(v3.x, true);
                a45 += __builtin_amdgcn_cvt_pk_f32_fp8(v3.y, false);
                a67 += __builtin_amdgcn_cvt_pk_f32_fp8(v3.y, true);
            }
            for (; i + 4 <= cnt; i += 4) {
                int s = __shfl(myc, i + g);
                uint2 v = P2[(size_t)s * 16 + li];
                a01 += __builtin_amdgcn_cvt_pk_f32_fp8(v.x, false);
                a23 += __builtin_amdgcn_cvt_pk_f32_fp8(v.x, true);
                a45 += __builtin_amdgcn_cvt_pk_f32_fp8(v.y, false);
                a67 += __builtin_amdgcn_cvt_pk_f32_fp8(v.y, true);
            }
            if (i < cnt) {
                int ie = i + g;
                int s = __shfl(myc, ie < cnt ? ie : cnt - 1);
                uint2 v = P2[(size_t)s * 16 + li];
                if (ie < cnt) {
                    a01 += __builtin_amdgcn_cvt_pk_f32_fp8(v.x, false);
                    a23 += __builtin_amdgcn_cvt_pk_f32_fp8(v.x, true);
                    a45 += __builtin_amdgcn_cvt_pk_f32_fp8(v.y, false);
                    a67 += __builtin_amdgcn_cvt_pk_f32_fp8(v.y, true);
                }
            }
        }
        // cross-group butterfly: combine the 4 16-lane groups
        a01.x += __shfl_xor(a01.x, 16); a01.y += __shfl_xor(a01.y, 16);
        a23.x += __shfl_xor(a23.x, 16); a23.y += __shfl_xor(a23.y, 16);
        a45.x += __shfl_xor(a45.x, 16); a45.y += __shfl_xor(a45.y, 16);
        a67.x += __shfl_xor(a67.x, 16); a67.y += __shfl_xor(a67.y, 16);
        a01.x += __shfl_xor(a01.x, 32); a01.y += __shfl_xor(a01.y, 32);
        a23.x += __shfl_xor(a23.x, 32); a23.y += __shfl_xor(a23.y, 32);
        a45.x += __shfl_xor(a45.x, 32); a45.y += __shfl_xor(a45.y, 32);
        a67.x += __shfl_xor(a67.x, 32); a67.y += __shfl_xor(a67.y, 32);
        float idg = inv_deg[node];
        floatx2 r = (g == 0) ? a01 : (g == 1) ? a23 : (g == 2) ? a45 : a67;
        float* o = out + (size_t)node * OSTRIDE + li * 8 + g * 2;
        float2 q = *(const float2*)o;
        float rx = r.x * idg + q.x;
        float ry = r.y * idg + q.y;
        float2 w; w.x = rx; w.y = ry;
        *(float2*)o = w;
        if (STATS) { sx += rx; sy += ry; qx += rx * rx; qy += ry * ry; }
    }
    if (STATS) {
        __shared__ float S[4][128], Q[4][128];
        int c0 = li * 8 + g * 2;
        S[wid][c0] = sx; S[wid][c0 + 1] = sy;
        Q[wid][c0] = qx; Q[wid][c0 + 1] = qy;
        __syncthreads();
        int t = threadIdx.x;
        if (t < 128) {
            atomicAdd(&colsum[t], S[0][t] + S[1][t] + S[2][t] + S[3][t]);
            atomicAdd(&colsumsq[t], Q[0][t] + Q[1][t] + Q[2][t] + Q[3][t]);
        }
    }
}

__global__ void k_bnfin(const float* __restrict__ colsum, const float* __restrict__ colsumsq,
                        const float* __restrict__ gamma, const float* __restrict__ beta,
                        float* __restrict__ scale, float* __restrict__ shift, int n) {
    int t = threadIdx.x;
    float inv_n = 1.0f / (float)n;
    float mu = colsum[t] * inv_n;
    float var = colsumsq[t] * inv_n - mu * mu;
    float sc = gamma[t] * rsqrtf(var + 1e-5f);
    scale[t] = sc;
    shift[t] = beta[t] - mu * sc;
}

// ---------- GEMM1: fused BN-affine + ReLU + [Y|Z] ----------
__launch_bounds__(256, 2)
__global__ void k_gemm1(const float* __restrict__ h, const unsigned short* __restrict__ W1f,
                        const float* __restrict__ bnscale, const float* __restrict__ bnshift,
                        const float* __restrict__ b1p, const float* __restrict__ b1n,
                        unsigned char* __restrict__ Y, float* __restrict__ out, int n) {
    __shared__ unsigned short As[64 * 264];
    __shared__ float sc[256], sh[256];
    int t = threadIdx.x; int wave = t >> 6; int lane = t & 63;
    sc[t] = bnscale[t]; sh[t] = bnshift[t];
    const short8* wf = (const short8*)W1f;
    int bx = blockIdx.x;
    int rowbase = (bx >> 1) * 64;
    int ch = bx & 1;  // column half: 0 -> cols 0..127, 1 -> cols 128..255
    bool full = (rowbase + 64 <= n);
    __syncthreads();
    if (full) {
#pragma unroll
        for (int it = 0; it < 8; it++) {
            int seg = it * 256 + t;
            int r = seg >> 5; int k0 = (seg & 31) * 8;
            const float* hp = h + (size_t)(rowbase + r) * 256 + k0;
            float4 a = *(const float4*)hp;
            float4 b = *(const float4*)(hp + 4);
            float vv[8] = {a.x, a.y, a.z, a.w, b.x, b.y, b.z, b.w};
            union { unsigned short u[8]; uint4 q; } pk;
#pragma unroll
            for (int q2 = 0; q2 < 8; q2++) {
                float v = vv[q2] * sc[k0 + q2] + sh[k0 + q2];
                v = v > 0.f ? v : 0.f;
                pk.u[q2] = f2bf(v);
            }
            *(uint4*)(&As[r * 264 + k0]) = pk.q;
        }
    } else {
#pragma unroll
        for (int it = 0; it < 8; it++) {
            int seg = it * 256 + t;
            int r = seg >> 5; int k0 = (seg & 31) * 8;
            int row = rowbase + r;
            union { unsigned short u[8]; uint4 q; } pk;
            if (row < n) {
                float4 a = *(const float4*)(h + (size_t)row * 256 + k0);
                float4 b = *(const float4*)(h + (size_t)row * 256 + k0 + 4);
                float vv[8] = {a.x, a.y, a.z, a.w, b.x, b.y, b.z, b.w};
#pragma unroll
                for (int q2 = 0; q2 < 8; q2++) {
                    float v = vv[q2] * sc[k0 + q2] + sh[k0 + q2];
                    v = v > 0.f ? v : 0.f;
                    pk.u[q2] = f2bf(v);
                }
            } else {
#pragma unroll
                for (int q2 = 0; q2 < 8; q2++) pk.u[q2] = 0;
            }
            *(uint4*)(&As[r * 264 + k0]) = pk.q;
        }
    }
    __syncthreads();
    int m = lane & 15; int quad = lane >> 4;
    short8 Bf[2][8];
    int ctbase = ch * 8 + wave * 2;
#pragma unroll
    for (int i = 0; i < 2; i++) {
#pragma unroll
        for (int ks = 0; ks < 8; ks++) Bf[i][ks] = wf[((ctbase + i) * 8 + ks) * 64 + lane];
    }
#pragma unroll
    for (int rt = 0; rt < 4; rt++) {
        floatx4 acc[2];
        acc[0] = (floatx4){0.f, 0.f, 0.f, 0.f};
        acc[1] = (floatx4){0.f, 0.f, 0.f, 0.f};
#pragma unroll
        for (int ks = 0; ks < 8; ks++) {
            short8 a = *(const short8*)(&As[(rt * 16 + m) * 264 + ks * 32 + quad * 8]);
            acc[0] = __builtin_amdgcn_mfma_f32_16x16x32_bf16(a, Bf[0][ks], acc[0], 0, 0, 0);
            acc[1] = __builtin_amdgcn_mfma_f32_16x16x32_bf16(a, Bf[1][ks], acc[1], 0, 0, 0);
        }
        int r0 = rowbase + rt * 16 + quad * 4;
#pragma unroll
        for (int i = 0; i < 2; i++) {
            int colg = ch * 128 + wave * 32 + i * 16 + m;
            if (full) {
                if (colg < 128) {
                    unsigned char* yp = Y + (size_t)r0 * 128 + colg;
                    yp[0]   = f2fp8(acc[i][0]);
                    yp[128] = f2fp8(acc[i][1]);
                    yp[256] = f2fp8(acc[i][2]);
                    yp[384] = f2fp8(acc[i][3]);
                } else {
                    float bias = (colg < 192) ? b1p[colg - 128] : b1n[colg - 192];
                    float* op = out + (size_t)r0 * 128 + (colg - 128);
                    op[0]   = acc[i][0] + bias;
                    op[128] = acc[i][1] + bias;
                    op[256] = acc[i][2] + bias;
                    op[384] = acc[i][3] + bias;
                }
            } else {
#pragma unroll
                for (int rr = 0; rr < 4; rr++) {
                    int row = r0 + rr;
                    if (row < n) {
                        float v = acc[i][rr];
                        if (colg < 128) {
                            Y[(size_t)row * 128 + colg] = f2fp8(v);
                        } else {
                            float bias = (colg < 192) ? b1p[colg - 128] : b1n[colg - 192];
                            out[(size_t)row * 128 + (colg - 128)] = v + bias;
                        }
                    }
                }
            }
        }
    }
}

extern "C" void kernel_launch(void* const* d_in, const int* in_sizes, int n_in,
                              void* d_out, int out_size, void* d_ws, size_t ws_size,
                              hipStream_t stream) {
    const float* x        = (const float*)d_in[0];
    const void*  ei_raw   = d_in[1];
    const float* w0_pos_l = (const float*)d_in[2];
    const float* w0_pos_r = (const float*)d_in[3];
    const float* b0_pos_r = (const float*)d_in[4];
    const float* w0_neg_r = (const float*)d_in[5];
    const float* b0_neg_r = (const float*)d_in[6];
    const float* bn_gamma = (const float*)d_in[7];
    const float* bn_beta  = (const float*)d_in[8];
    const float* w1_pos_l = (const float*)d_in[9];
    const float* w1_pos_r = (const float*)d_in[10];
    const float* b1_pos_r = (const float*)d_in[11];
    const float* w1_neg_l = (const float*)d_in[12];
    const float* w1_neg_r = (const float*)d_in[13];
    const float* b1_neg_r = (const float*)d_in[14];
    float* out = (float*)d_out;
    int N = in_sizes[0] / 128;
    int E = in_sizes[1] / 2;
    int NB = (N + 511) >> 9;  // coarse buckets of 512 dst nodes

    char* ws = (char*)d_ws;
    size_t off = 0;
    auto carve = [&](size_t bytes) -> char* {
        char* p = ws + off;
        off += (bytes + 255) & ~(size_t)255;
        return p;
    };
    int*      eflag   = (int*)carve(256);
    int*      src     = (int*)carve((size_t)E * 4);
    int*      dst     = (int*)carve((size_t)E * 4);
    int*      bhist   = (int*)carve((size_t)NB * 4);
    int*      bbase   = (int*)carve((size_t)(NB + 1) * 4);
    int*      pcur    = (int*)carve((size_t)NB * 4);
    int*      row_ptr = (int*)carve((size_t)(N + 1) * 4);
    float*    inv_deg = (float*)carve((size_t)N * 4);
    unsigned* pairs   = (unsigned*)carve((size_t)E * 4);
    int*      ecol    = (int*)carve((size_t)E * 4);
    unsigned char* P  = (unsigned char*)carve((size_t)N * 128);
    float* h          = (float*)carve((size_t)N * 256 * 4);
    unsigned char* Yb = (unsigned char*)carve((size_t)N * 128);
    unsigned short* W0f = (unsigned short*)carve(24 * 4 * 64 * 8 * 2);
    unsigned short* W1f = (unsigned short*)carve(16 * 8 * 64 * 8 * 2);
    float* colsum   = (float*)carve(2 * 256 * 4);
    float* colsumsq = colsum + 256;
    float* bnscale  = (float*)carve(256 * 4);
    float* bnshift  = (float*)carve(256 * 4);

    hipMemsetAsync(bhist, 0, (size_t)NB * 4, stream);
    hipMemsetAsync(colsum, 0, 2 * 256 * 4, stream);

    int nwords = 2 * E < 32768 ? 2 * E : 32768;
    k_detect<<<1, 256, 0, stream>>>((const unsigned*)ei_raw, eflag, nwords);
    k_remap_hist<<<(E + 4095) / 4096, 1024, 0, stream>>>(ei_raw, eflag, src, dst, bhist, E, N, NB);
    k_offsets<<<1, 256, 0, stream>>>(bhist, bbase, pcur, row_ptr, E, N, NB);
    k_phase1<<<(E + 16383) / 16384, 1024, 0, stream>>>(src, dst, pcur, pairs, E, NB);
    k_phase2<<<NB, 512, 0, stream>>>(pairs, bbase, row_ptr, inv_deg, ecol, N);

    k_w0prep<<<24, 256, 0, stream>>>(w0_pos_l, w0_pos_r, w0_neg_r, W0f);
    k_w1prep<<<32, 256, 0, stream>>>(w1_pos_l, w1_neg_l, w1_pos_r, w1_neg_r, W1f);

    int gb = (N + 63) / 64;
    k_gemm0<<<gb * 2, 256, 0, stream>>>(x, W0f, b0_pos_r, b0_neg_r, P, h, colsum, colsumsq, N);
    k_agg<256, true><<<2048, 256, 0, stream>>>(row_ptr, ecol, inv_deg, (const uint2*)P, h,
                                               colsum, colsumsq, N);
    k_bnfin<<<1, 256, 0, stream>>>(colsum, colsumsq, bn_gamma, bn_beta, bnscale, bnshift, N);
    k_gemm1<<<gb * 2, 256, 0, stream>>>(h, W1f, bnscale, bnshift, b1_pos_r, b1_neg_r, Yb, out, N);
    k_agg<128, false><<<2048, 256, 0, stream>>>(row_ptr, ecol, inv_deg, (const uint2*)Yb, out,
                                                nullptr, nullptr, N);
}